// Round 4
// baseline (118.209 us; speedup 1.0000x reference)
//
#include <hip/hip_runtime.h>

#define NN 1024
#define DFEAT 6
#define TSTEPS 60
#define HID 64
#define RREL 60
#define SENT -1.0e30f
#define NSTREAM (NN * 4)   // stream blocks come FIRST in dispatch order

// Fused kernel: blocks [0, 4096) stream rel (HBM-bound, dispatched first so
// they own the CUs); blocks [4096, 5120) run the GRU (latency-bound, hides
// under the stream tail). launch_bounds(256,4): cap 128 VGPR -> whh[64] fits
// in registers (R3 defect: VGPR=56 forced reloads), 16 waves/CU.
__global__ __launch_bounds__(256, 4) void fused_kernel(
    const float* __restrict__ x,      // (1024, 360)
    const float* __restrict__ W_ih,   // (192, 6)
    const float* __restrict__ W_hh,   // (192, 64)
    const float* __restrict__ b_ih,   // (192)
    const float* __restrict__ b_hh,   // (192)
    const float* __restrict__ w_att,  // (188)
    const float* __restrict__ rel,    // (1024, 1024, 60)
    float* __restrict__ h_last,       // (1024, 64)
    float* __restrict__ s_i,          // (1024)
    float* __restrict__ s_j,          // (1024)
    float* __restrict__ temp)         // (1024, 1024): srel or SENT
{
    if (blockIdx.x < NSTREAM) {
        // ---------------- rel stream part ----------------
        const int b = blockIdx.x;                 // 0..4095
        const int i = b >> 2;
        const int j = ((b & 3) << 8) + threadIdx.x;
        const size_t pair = (size_t)i * NN + j;

        float wrel[RREL];                          // uniform
#pragma unroll
        for (int r = 0; r < RREL; ++r) wrel[r] = w_att[2 * HID + r];

        const float4* rp = reinterpret_cast<const float4*>(rel + pair * RREL);
        float srel = 0.0f, msum = 0.0f;
#pragma unroll
        for (int r4 = 0; r4 < RREL / 4; ++r4) {
            float4 v = rp[r4];
            srel += v.x * wrel[4*r4+0] + v.y * wrel[4*r4+1]
                  + v.z * wrel[4*r4+2] + v.w * wrel[4*r4+3];
            msum += v.x + v.y + v.z + v.w;
        }
        temp[pair] = (msum != 0.0f) ? srel : SENT;
        return;
    }

    // ---------------- GRU part ----------------
    const int n = blockIdx.x - NSTREAM;
    const int g = threadIdx.x;

    __shared__ __align__(16) float x_sh[DFEAT * TSTEPS];
    __shared__ __align__(16) float h_sh[HID];
    __shared__ float gi_sh[192];
    __shared__ float gh_sh[192];

    for (int idx = g; idx < DFEAT * TSTEPS; idx += 256)
        x_sh[idx] = x[(size_t)n * (DFEAT * TSTEPS) + idx];

    float whh[HID];
    float wih[DFEAT];
    float bih = 0.0f, bhh = 0.0f;
    if (g < 192) {
#pragma unroll
        for (int k4 = 0; k4 < HID / 4; ++k4) {
            float4 w = *reinterpret_cast<const float4*>(&W_hh[g * HID + k4 * 4]);
            whh[k4 * 4 + 0] = w.x; whh[k4 * 4 + 1] = w.y;
            whh[k4 * 4 + 2] = w.z; whh[k4 * 4 + 3] = w.w;
        }
#pragma unroll
        for (int d = 0; d < DFEAT; ++d) wih[d] = W_ih[g * DFEAT + d];
        bih = b_ih[g];
        bhh = b_hh[g];
    }

    if (g < HID) h_sh[g] = 0.0f;
    __syncthreads();

    for (int t = 0; t < TSTEPS; ++t) {
        if (g < 192) {
            float gi = bih;
#pragma unroll
            for (int d = 0; d < DFEAT; ++d) gi += x_sh[d * TSTEPS + t] * wih[d];

            float gh = bhh;
#pragma unroll
            for (int k4 = 0; k4 < HID / 4; ++k4) {
                float4 hv = *reinterpret_cast<const float4*>(&h_sh[k4 * 4]);
                gh += hv.x * whh[k4 * 4 + 0] + hv.y * whh[k4 * 4 + 1]
                    + hv.z * whh[k4 * 4 + 2] + hv.w * whh[k4 * 4 + 3];
            }
            gi_sh[g] = gi;
            gh_sh[g] = gh;
        }
        __syncthreads();

        if (g < HID) {
            float ir = gi_sh[g],        hr = gh_sh[g];
            float iz = gi_sh[HID + g],  hz = gh_sh[HID + g];
            float in_ = gi_sh[2*HID + g], hn = gh_sh[2*HID + g];
            float r = 1.0f / (1.0f + __expf(-(ir + hr)));
            float z = 1.0f / (1.0f + __expf(-(iz + hz)));
            float a = in_ + r * hn;                 // tanh via exp2-form
            float p = __expf(2.0f * a);
            float nn_ = (p - 1.0f) / (p + 1.0f);
            float hold = h_sh[g];
            h_sh[g] = (1.0f - z) * nn_ + z * hold;
        }
        __syncthreads();
    }

    if (g < HID) {
        float hv = h_sh[g];
        h_last[(size_t)n * HID + g] = hv;
        float pi = hv * w_att[g];
        float pj = hv * w_att[HID + g];
#pragma unroll
        for (int off = 32; off > 0; off >>= 1) {
            pi += __shfl_down(pi, off);
            pj += __shfl_down(pj, off);
        }
        if (g == 0) { s_i[n] = pi; s_j[n] = pj; }
    }
}

// --------- Kernel 2: weight assembly + softmax + agg matvec + FC -------------
__global__ __launch_bounds__(256) void row_kernel(
    const float* __restrict__ temp,   // (1024, 1024): srel or SENT
    const float* __restrict__ s_i,    // (1024)
    const float* __restrict__ s_j,    // (1024)
    const float* __restrict__ b_att,  // (1)
    const float* __restrict__ h_last, // (1024, 64)
    const float* __restrict__ W_fc,   // (128)
    const float* __restrict__ b_fc,   // (1)
    float* __restrict__ out)          // (1024)
{
    const int i = blockIdx.x;
    const int tid = threadIdx.x;

    __shared__ __align__(16) float pm_sh[NN];
    __shared__ float red_sh[256];

    const float si_b = s_i[i] + b_att[0];
    float4 sv = reinterpret_cast<const float4*>(temp + (size_t)i * NN)[tid];
    float4 sj = reinterpret_cast<const float4*>(s_j)[tid];

    float tvv[4];
    {
        float srels[4] = {sv.x, sv.y, sv.z, sv.w};
        float sjs[4]   = {sj.x, sj.y, sj.z, sj.w};
#pragma unroll
        for (int c = 0; c < 4; ++c) {
            float w = si_b + sjs[c] + srels[c];
            w = (w >= 0.0f) ? w : 0.01f * w;
            float tv = (srels[c] != SENT) ? w : 0.0f;   // mask * weight
            tvv[c] = (tv == 0.0f) ? -10000.0f : tv;
        }
    }
    float m = fmaxf(fmaxf(tvv[0], tvv[1]), fmaxf(tvv[2], tvv[3]));
    red_sh[tid] = m;
    __syncthreads();
    for (int s = 128; s > 0; s >>= 1) {
        if (tid < s) red_sh[tid] = fmaxf(red_sh[tid], red_sh[tid + s]);
        __syncthreads();
    }
    const float M = red_sh[0];
    __syncthreads();

    float lsum = 0.0f;
    float4 pmv;
    {
        float e0 = __expf(tvv[0] - M), e1 = __expf(tvv[1] - M);
        float e2 = __expf(tvv[2] - M), e3 = __expf(tvv[3] - M);
        lsum = e0 + e1 + e2 + e3;                  // denom over ALL j
        pmv.x = (tvv[0] != -10000.0f) ? e0 : 0.0f;
        pmv.y = (tvv[1] != -10000.0f) ? e1 : 0.0f;
        pmv.z = (tvv[2] != -10000.0f) ? e2 : 0.0f;
        pmv.w = (tvv[3] != -10000.0f) ? e3 : 0.0f;
    }
    reinterpret_cast<float4*>(pm_sh)[tid] = pmv;

    red_sh[tid] = lsum;
    __syncthreads();
    for (int s = 128; s > 0; s >>= 1) {
        if (tid < s) red_sh[tid] += red_sh[tid + s];
        __syncthreads();
    }
    const float invS = 1.0f / red_sh[0];
    __syncthreads();

    // agg[h] = invS * sum_j pm[j] * h_last[j][h]
    const int h = tid & (HID - 1);
    const int grp = tid >> 6;                      // 4 groups x 256 j each
    float part = 0.0f;
    const float* hl = h_last + (size_t)grp * 256 * HID + h;
    const float* pm = pm_sh + grp * 256;
    for (int jc = 0; jc < 256; ++jc)
        part += pm[jc] * hl[(size_t)jc * HID];

    red_sh[tid] = part;
    __syncthreads();

    if (tid < HID) {
        float agg = (red_sh[tid] + red_sh[HID + tid]
                   + red_sh[2 * HID + tid] + red_sh[3 * HID + tid]) * invS;
        float o = h_last[(size_t)i * HID + tid] * W_fc[tid] + agg * W_fc[HID + tid];
#pragma unroll
        for (int off = 32; off > 0; off >>= 1) o += __shfl_down(o, off);
        if (tid == 0) out[i] = o + b_fc[0];
    }
}

extern "C" void kernel_launch(void* const* d_in, const int* in_sizes, int n_in,
                              void* d_out, int out_size, void* d_ws, size_t ws_size,
                              hipStream_t stream) {
    const float* x     = (const float*)d_in[0];
    const float* rel   = (const float*)d_in[1];
    const float* W_ih  = (const float*)d_in[2];
    const float* W_hh  = (const float*)d_in[3];
    const float* b_ih  = (const float*)d_in[4];
    const float* b_hh  = (const float*)d_in[5];
    const float* w_att = (const float*)d_in[6];
    const float* b_att = (const float*)d_in[7];
    const float* W_fc  = (const float*)d_in[8];
    const float* b_fc  = (const float*)d_in[9];

    float* ws     = (float*)d_ws;
    float* h_last = ws;                      // 1024*64
    float* s_i    = ws + NN * HID;           // 1024
    float* s_j    = ws + NN * HID + NN;      // 1024
    float* temp   = ws + NN * HID + 2 * NN;  // 1024*1024

    fused_kernel<<<NSTREAM + NN, 256, 0, stream>>>(
        x, W_ih, W_hh, b_ih, b_hh, w_att, rel, h_last, s_i, s_j, temp);
    row_kernel<<<NN, 256, 0, stream>>>(temp, s_i, s_j, b_att, h_last,
                                       W_fc, b_fc, (float*)d_out);
}

// Round 5
// 102.410 us; speedup vs baseline: 1.1543x; 1.1543x over previous
//
#include <hip/hip_runtime.h>

#define NN 1024
#define DFEAT 6
#define TSTEPS 60
#define HID 64
#define RREL 60
#define SENT -1.0e30f

// 16-lane-row rotate-reduce via DPP (no LDS traffic).
__device__ __forceinline__ float row16_reduce_add(float x) {
    int t;
    t = __builtin_amdgcn_update_dpp(0, __float_as_int(x), 0x128, 0xf, 0xf, false); // row_ror:8
    x += __int_as_float(t);
    t = __builtin_amdgcn_update_dpp(0, __float_as_int(x), 0x124, 0xf, 0xf, false); // row_ror:4
    x += __int_as_float(t);
    t = __builtin_amdgcn_update_dpp(0, __float_as_int(x), 0x122, 0xf, 0xf, false); // row_ror:2
    x += __int_as_float(t);
    t = __builtin_amdgcn_update_dpp(0, __float_as_int(x), 0x121, 0xf, 0xf, false); // row_ror:1
    x += __int_as_float(t);
    return x; // all 16 lanes of the row hold the sum
}

// Fused kernel: blocks [0,1024) = GRU (dispatched first; latency-bound, hides
// under the stream). Blocks [1024,2048) = rel stream, one i-row per block.
// Stream layout: 16 lanes per j-row (chunk = lane&15 reads float4 #chunk of
// the 240B row) -> one wave instruction spans 4 consecutive rows = 960B
// contiguous = ~8 line-requests (vs 64 for the old 240B-strided mapping).
__global__ __launch_bounds__(256) void fused_kernel(
    const float* __restrict__ x,      // (1024, 360)
    const float* __restrict__ W_ih,   // (192, 6)
    const float* __restrict__ W_hh,   // (192, 64)
    const float* __restrict__ b_ih,   // (192)
    const float* __restrict__ b_hh,   // (192)
    const float* __restrict__ w_att,  // (188)
    const float* __restrict__ rel,    // (1024, 1024, 60)
    float* __restrict__ h_last,       // (1024, 64)
    float* __restrict__ s_i,          // (1024)
    float* __restrict__ s_j,          // (1024)
    float* __restrict__ temp)         // (1024, 1024): srel or SENT
{
    if (blockIdx.x >= NN) {
        // ---------------- rel stream part ----------------
        const int i    = blockIdx.x - NN;
        const int lane = threadIdx.x & 63;
        const int wv   = threadIdx.x >> 6;        // wave 0..3 -> j quarter
        const int rr   = lane >> 4;               // row-in-group 0..3
        const int chunk = lane & 15;              // float4 index in row
        const int cc   = (chunk < 15) ? chunk : 14;
        const bool c15 = (chunk == 15);

        float4 wr = *reinterpret_cast<const float4*>(&w_att[2 * HID + cc * 4]);
        if (c15) { wr.x = 0.0f; wr.y = 0.0f; wr.z = 0.0f; wr.w = 0.0f; }

        const float* rowbase = rel + (size_t)i * (NN * RREL);

        for (int it = 0; it < 16; ++it) {
            const int jb = wv * 256 + it * 16 + rr;   // + u*4 below
            float4 v[4];
#pragma unroll
            for (int u = 0; u < 4; ++u) {
                const float* p = rowbase + (size_t)(jb + u * 4) * RREL + cc * 4;
                v[u] = *reinterpret_cast<const float4*>(p);
            }
#pragma unroll
            for (int u = 0; u < 4; ++u) {
                float pd = v[u].x * wr.x + v[u].y * wr.y
                         + v[u].z * wr.z + v[u].w * wr.w;
                float pm = c15 ? 0.0f : (v[u].x + v[u].y + v[u].z + v[u].w);
                pd = row16_reduce_add(pd);
                pm = row16_reduce_add(pm);
                if (chunk == 0)
                    temp[(size_t)i * NN + jb + u * 4] = (pm != 0.0f) ? pd : SENT;
            }
        }
        return;
    }

    // ---------------- GRU part (identical to R3) ----------------
    const int n = blockIdx.x;
    const int g = threadIdx.x;

    __shared__ __align__(16) float x_sh[DFEAT * TSTEPS];
    __shared__ __align__(16) float h_sh[HID];
    __shared__ float gi_sh[192];
    __shared__ float gh_sh[192];

    for (int idx = g; idx < DFEAT * TSTEPS; idx += 256)
        x_sh[idx] = x[(size_t)n * (DFEAT * TSTEPS) + idx];

    float whh[HID];
    float wih[DFEAT];
    float bih = 0.0f, bhh = 0.0f;
    if (g < 192) {
#pragma unroll
        for (int k4 = 0; k4 < HID / 4; ++k4) {
            float4 w = *reinterpret_cast<const float4*>(&W_hh[g * HID + k4 * 4]);
            whh[k4 * 4 + 0] = w.x; whh[k4 * 4 + 1] = w.y;
            whh[k4 * 4 + 2] = w.z; whh[k4 * 4 + 3] = w.w;
        }
#pragma unroll
        for (int d = 0; d < DFEAT; ++d) wih[d] = W_ih[g * DFEAT + d];
        bih = b_ih[g];
        bhh = b_hh[g];
    }

    if (g < HID) h_sh[g] = 0.0f;
    __syncthreads();

    for (int t = 0; t < TSTEPS; ++t) {
        if (g < 192) {
            float gi = bih;
#pragma unroll
            for (int d = 0; d < DFEAT; ++d) gi += x_sh[d * TSTEPS + t] * wih[d];

            float gh = bhh;
#pragma unroll
            for (int k4 = 0; k4 < HID / 4; ++k4) {
                float4 hv = *reinterpret_cast<const float4*>(&h_sh[k4 * 4]);
                gh += hv.x * whh[k4 * 4 + 0] + hv.y * whh[k4 * 4 + 1]
                    + hv.z * whh[k4 * 4 + 2] + hv.w * whh[k4 * 4 + 3];
            }
            gi_sh[g] = gi;
            gh_sh[g] = gh;
        }
        __syncthreads();

        if (g < HID) {
            float ir = gi_sh[g],        hr = gh_sh[g];
            float iz = gi_sh[HID + g],  hz = gh_sh[HID + g];
            float in_ = gi_sh[2*HID + g], hn = gh_sh[2*HID + g];
            float r = 1.0f / (1.0f + __expf(-(ir + hr)));
            float z = 1.0f / (1.0f + __expf(-(iz + hz)));
            float nn_ = tanhf(in_ + r * hn);
            float hold = h_sh[g];
            h_sh[g] = (1.0f - z) * nn_ + z * hold;
        }
        __syncthreads();
    }

    if (g < HID) {
        float hv = h_sh[g];
        h_last[(size_t)n * HID + g] = hv;
        float pi = hv * w_att[g];
        float pj = hv * w_att[HID + g];
#pragma unroll
        for (int off = 32; off > 0; off >>= 1) {
            pi += __shfl_down(pi, off);
            pj += __shfl_down(pj, off);
        }
        if (g == 0) { s_i[n] = pi; s_j[n] = pj; }
    }
}

// --------- Kernel 2: weight assembly + softmax + agg matvec + FC -------------
__global__ __launch_bounds__(256) void row_kernel(
    const float* __restrict__ temp,   // (1024, 1024): srel or SENT
    const float* __restrict__ s_i,    // (1024)
    const float* __restrict__ s_j,    // (1024)
    const float* __restrict__ b_att,  // (1)
    const float* __restrict__ h_last, // (1024, 64)
    const float* __restrict__ W_fc,   // (128)
    const float* __restrict__ b_fc,   // (1)
    float* __restrict__ out)          // (1024)
{
    const int i = blockIdx.x;
    const int tid = threadIdx.x;

    __shared__ __align__(16) float pm_sh[NN];
    __shared__ float red_sh[256];

    const float si_b = s_i[i] + b_att[0];
    float4 sv = reinterpret_cast<const float4*>(temp + (size_t)i * NN)[tid];
    float4 sj = reinterpret_cast<const float4*>(s_j)[tid];

    float tvv[4];
    {
        float srels[4] = {sv.x, sv.y, sv.z, sv.w};
        float sjs[4]   = {sj.x, sj.y, sj.z, sj.w};
#pragma unroll
        for (int c = 0; c < 4; ++c) {
            float w = si_b + sjs[c] + srels[c];
            w = (w >= 0.0f) ? w : 0.01f * w;
            float tv = (srels[c] != SENT) ? w : 0.0f;   // mask * weight
            tvv[c] = (tv == 0.0f) ? -10000.0f : tv;
        }
    }
    float m = fmaxf(fmaxf(tvv[0], tvv[1]), fmaxf(tvv[2], tvv[3]));
    red_sh[tid] = m;
    __syncthreads();
    for (int s = 128; s > 0; s >>= 1) {
        if (tid < s) red_sh[tid] = fmaxf(red_sh[tid], red_sh[tid + s]);
        __syncthreads();
    }
    const float M = red_sh[0];
    __syncthreads();

    float lsum = 0.0f;
    float4 pmv;
    {
        float e0 = __expf(tvv[0] - M), e1 = __expf(tvv[1] - M);
        float e2 = __expf(tvv[2] - M), e3 = __expf(tvv[3] - M);
        lsum = e0 + e1 + e2 + e3;                  // denom over ALL j
        pmv.x = (tvv[0] != -10000.0f) ? e0 : 0.0f;
        pmv.y = (tvv[1] != -10000.0f) ? e1 : 0.0f;
        pmv.z = (tvv[2] != -10000.0f) ? e2 : 0.0f;
        pmv.w = (tvv[3] != -10000.0f) ? e3 : 0.0f;
    }
    reinterpret_cast<float4*>(pm_sh)[tid] = pmv;

    red_sh[tid] = lsum;
    __syncthreads();
    for (int s = 128; s > 0; s >>= 1) {
        if (tid < s) red_sh[tid] += red_sh[tid + s];
        __syncthreads();
    }
    const float invS = 1.0f / red_sh[0];
    __syncthreads();

    // agg[h] = invS * sum_j pm[j] * h_last[j][h]
    const int h = tid & (HID - 1);
    const int grp = tid >> 6;                      // 4 groups x 256 j each
    float part = 0.0f;
    const float* hl = h_last + (size_t)grp * 256 * HID + h;
    const float* pm = pm_sh + grp * 256;
    for (int jc = 0; jc < 256; ++jc)
        part += pm[jc] * hl[(size_t)jc * HID];

    red_sh[tid] = part;
    __syncthreads();

    if (tid < HID) {
        float agg = (red_sh[tid] + red_sh[HID + tid]
                   + red_sh[2 * HID + tid] + red_sh[3 * HID + tid]) * invS;
        float o = h_last[(size_t)i * HID + tid] * W_fc[tid] + agg * W_fc[HID + tid];
#pragma unroll
        for (int off = 32; off > 0; off >>= 1) o += __shfl_down(o, off);
        if (tid == 0) out[i] = o + b_fc[0];
    }
}

extern "C" void kernel_launch(void* const* d_in, const int* in_sizes, int n_in,
                              void* d_out, int out_size, void* d_ws, size_t ws_size,
                              hipStream_t stream) {
    const float* x     = (const float*)d_in[0];
    const float* rel   = (const float*)d_in[1];
    const float* W_ih  = (const float*)d_in[2];
    const float* W_hh  = (const float*)d_in[3];
    const float* b_ih  = (const float*)d_in[4];
    const float* b_hh  = (const float*)d_in[5];
    const float* w_att = (const float*)d_in[6];
    const float* b_att = (const float*)d_in[7];
    const float* W_fc  = (const float*)d_in[8];
    const float* b_fc  = (const float*)d_in[9];

    float* ws     = (float*)d_ws;
    float* h_last = ws;                      // 1024*64
    float* s_i    = ws + NN * HID;           // 1024
    float* s_j    = ws + NN * HID + NN;      // 1024
    float* temp   = ws + NN * HID + 2 * NN;  // 1024*1024

    fused_kernel<<<NN + NN, 256, 0, stream>>>(
        x, W_ih, W_hh, b_ih, b_hh, w_att, rel, h_last, s_i, s_j, temp);
    row_kernel<<<NN, 256, 0, stream>>>(temp, s_i, s_j, b_att, h_last,
                                       W_fc, b_fc, (float*)d_out);
}